// Round 9
// baseline (806.221 us; speedup 1.0000x reference)
//
#include <hip/hip_runtime.h>
#include <stdint.h>

// Problem constants (fixed shapes)
#define TT 8192      // tokens = B*S
#define HH 2048      // hidden dim
#define II 1408      // intermediate dim
#define IIC (II*2)   // 2816 combined (gate|up interleaved by 16 cols)
#define NE 8         // experts
#define NROWS (TT*2) // 16384 (token,slot) rows
#define BM 128       // row tile
#define BK 64        // k tile
#define BNC 256      // B-rows per tile (combined cols for gu, real for down)
#define MAX_SLOTS 144
#define NKT_GU (HH/BK)    // 32 K-tiles
#define NKT_DN (II/BK)    // 22 K-tiles
#define NYT_GU (IIC/BNC)  // 11 N-tiles
#define NYT_DN (HH/BNC)   // 8  N-tiles
#define SPX (MAX_SLOTS/8) // 18 slots per XCD

typedef unsigned short u16;
typedef __attribute__((ext_vector_type(8))) __bf16 bhalf8;
typedef __attribute__((ext_vector_type(4))) float f32x4;
typedef __attribute__((ext_vector_type(4))) float float4v;
typedef __attribute__((ext_vector_type(4))) int int4v;

__device__ __forceinline__ u16 f2bf(float f) {
  union { float f; unsigned u; } v; v.f = f;
  return (u16)((v.u + 0x7FFFu + ((v.u >> 16) & 1u)) >> 16);  // RNE
}

__device__ __forceinline__ void gld16(const void* g, void* l) {
  __builtin_amdgcn_global_load_lds(
      (const __attribute__((address_space(1))) unsigned int*)g,
      (__attribute__((address_space(3))) unsigned int*)l, 16, 0, 0);
}

__device__ __forceinline__ void barrier_raw() {
  asm volatile("" ::: "memory");
  __builtin_amdgcn_s_barrier();
  asm volatile("" ::: "memory");
}

// ---------------- hidden_states fp32 -> bf16 ----------------
__global__ __launch_bounds__(256) void k_cvt_hs(const float* __restrict__ in,
                                                u16* __restrict__ out) {
  size_t i = ((size_t)blockIdx.x * 256 + threadIdx.x) * 8;
  float4v a = *(const float4v*)(in + i);
  float4v b = *(const float4v*)(in + i + 4);
  u16 o[8];
  o[0] = f2bf(a.x); o[1] = f2bf(a.y); o[2] = f2bf(a.z); o[3] = f2bf(a.w);
  o[4] = f2bf(b.x); o[5] = f2bf(b.y); o[6] = f2bf(b.z); o[7] = f2bf(b.w);
  *(int4v*)(out + i) = *(const int4v*)o;
}

// ------- weight fp32 [E][R][C] -> bf16 transposed [E][C][R] (down) -------
__global__ __launch_bounds__(256) void k_tconv(const float* __restrict__ in,
                                               u16* __restrict__ out,
                                               int R, int C) {
  __shared__ float t[64][65];
  int e = blockIdx.z;
  int r0 = blockIdx.y * 64, c0 = blockIdx.x * 64;
  const float* ip = in + (size_t)e * R * C;
  u16* op = out + (size_t)e * R * C;
  int tid = threadIdx.x;
  int rr = tid >> 4, c4 = (tid & 15) * 4;
#pragma unroll
  for (int j = 0; j < 4; ++j) {
    float4v v = *(const float4v*)&ip[(size_t)(r0 + rr + 16 * j) * C + c0 + c4];
    t[rr + 16 * j][c4 + 0] = v.x;
    t[rr + 16 * j][c4 + 1] = v.y;
    t[rr + 16 * j][c4 + 2] = v.z;
    t[rr + 16 * j][c4 + 3] = v.w;
  }
  __syncthreads();
  int cc = tid >> 2, rb = (tid & 3) * 16;
  u16 buf[16];
#pragma unroll
  for (int i = 0; i < 16; ++i) buf[i] = f2bf(t[rb + i][cc]);
  u16* p = op + (size_t)(c0 + cc) * R + r0 + rb;
  *(int4v*)p = *(const int4v*)&buf[0];
  *(int4v*)(p + 8) = *(const int4v*)&buf[8];
}

// ------- gate/up fp32 [E][H][I] -> bf16 guw[E][IIC][H], 16-col interleave -------
// combined row for real col c: crow = (c>>4)*32 + is_up*16 + (c&15)
__global__ __launch_bounds__(256) void k_tconv_gu(const float* __restrict__ in,
                                                  u16* __restrict__ out,
                                                  int is_up) {
  __shared__ float t[64][65];
  const int R = HH, C = II;
  int e = blockIdx.z;
  int r0 = blockIdx.y * 64, c0 = blockIdx.x * 64;
  const float* ip = in + (size_t)e * R * C;
  u16* op = out + (size_t)e * IIC * R;
  int tid = threadIdx.x;
  int rr = tid >> 4, c4 = (tid & 15) * 4;
#pragma unroll
  for (int j = 0; j < 4; ++j) {
    float4v v = *(const float4v*)&ip[(size_t)(r0 + rr + 16 * j) * C + c0 + c4];
    t[rr + 16 * j][c4 + 0] = v.x;
    t[rr + 16 * j][c4 + 1] = v.y;
    t[rr + 16 * j][c4 + 2] = v.z;
    t[rr + 16 * j][c4 + 3] = v.w;
  }
  __syncthreads();
  int cc = tid >> 2, rb = (tid & 3) * 16;
  u16 buf[16];
#pragma unroll
  for (int i = 0; i < 16; ++i) buf[i] = f2bf(t[rb + i][cc]);
  int c = c0 + cc;
  int crow = ((c >> 4) << 5) + (is_up << 4) + (c & 15);
  u16* p = op + (size_t)crow * R + r0 + rb;
  *(int4v*)p = *(const int4v*)&buf[0];
  *(int4v*)(p + 8) = *(const int4v*)&buf[8];
}

// ---------------- routing: gather rows by expert ----------------
__global__ __launch_bounds__(256) void k_route(const int* __restrict__ sel,
                                               const float* __restrict__ rw,
                                               int* __restrict__ token_idx,
                                               float* __restrict__ wrow,
                                               int* __restrict__ s_e,
                                               int* __restrict__ s_rs,
                                               int* __restrict__ s_rows) {
  __shared__ int cnt[NE], offs[NE + 1], cursor[NE];
  int tid = threadIdx.x;
  if (tid < NE) cnt[tid] = 0;
  __syncthreads();
  for (int i = tid; i < NROWS; i += 256) atomicAdd(&cnt[sel[i]], 1);
  __syncthreads();
  if (tid == 0) {
    int o = 0;
    for (int e = 0; e < NE; ++e) { offs[e] = o; o += cnt[e]; }
    offs[NE] = o;
    int ns = 0;
    for (int e = 0; e < NE; ++e) {
      for (int t = 0; t < cnt[e]; t += BM) {
        s_e[ns] = e;
        s_rs[ns] = offs[e] + t;
        s_rows[ns] = (cnt[e] - t < BM) ? (cnt[e] - t) : BM;
        ns++;
      }
    }
    for (; ns < MAX_SLOTS; ++ns) s_rows[ns] = 0;
  }
  __syncthreads();
  if (tid < NE) cursor[tid] = offs[tid];
  __syncthreads();
  for (int i = tid; i < NROWS; i += 256) {
    int e = sel[i];
    int r = atomicAdd(&cursor[e], 1);
    token_idx[r] = i >> 1;   // token id
    wrow[r] = rw[i];         // routing weight for this slot
  }
}

// ---------------- gate/up GEMM (8-phase, 512 thr) + SwiGLU ----------------
// 128x256 tile, triple-buffered LDS (144 KB), counted vmcnt(6) gates,
// 4 phases/K-tile of {ds_read || stage-issue -> barrier -> MFMA -> barrier}.
__global__ __launch_bounds__(512) void k_gu(const u16* __restrict__ hsb,
                                            const u16* __restrict__ guw,
                                            const int* __restrict__ token_idx,
                                            const float* __restrict__ wrow,
                                            const int* __restrict__ s_e,
                                            const int* __restrict__ s_rs,
                                            const int* __restrict__ s_rows,
                                            u16* __restrict__ act) {
  int f = blockIdx.x;
  int xcd = f & 7, pos = f >> 3;           // 1584 = 8*198
  int slot = xcd * SPX + pos / NYT_GU;
  int ytile = pos % NYT_GU;
  int nrows = s_rows[slot];
  if (nrows == 0) return;
  int e = s_e[slot], row0 = s_rs[slot];
  int i0c = ytile * BNC;     // combined col base
  int i0r = ytile * 128;     // real col base

  __shared__ alignas(16) u16 As[3][BM][BK];    // 48 KB
  __shared__ alignas(16) u16 Bs[3][BNC][BK];   // 96 KB

  int tid = threadIdx.x, lane = tid & 63, wid = tid >> 6;
  int l8 = lane >> 3, c8 = lane & 7, cs = c8 ^ l8;
  int wm = wid >> 2, wn = wid & 3;
  int l15 = lane & 15, l16 = lane >> 4;
  int cswz = l16 ^ (l15 & 7);              // ks0 read chunk; ks1 = cswz^4

  const u16* agp[2];
#pragma unroll
  for (int j = 0; j < 2; ++j) {
    int gr = row0 + wid * 16 + j * 8 + l8;
    if (gr > NROWS - 1) gr = NROWS - 1;
    agp[j] = hsb + (size_t)token_idx[gr] * HH + cs * 8;
  }
  const u16* bgp[4];
#pragma unroll
  for (int j = 0; j < 4; ++j) {
    int brow = i0c + wid * 32 + j * 8 + l8;
    bgp[j] = guw + ((size_t)e * IIC + brow) * HH + cs * 8;
  }

  f32x4 acc[4][4];
#pragma unroll
  for (int a = 0; a < 4; ++a)
#pragma unroll
    for (int b = 0; b < 4; ++b) acc[a][b] = (f32x4)0.0f;

  // prologue: stage tiles 0 and 1 (6 loads each per wave)
#pragma unroll
  for (int j = 0; j < 2; ++j) gld16(agp[j], &As[0][wid * 16 + j * 8][0]);
#pragma unroll
  for (int j = 0; j < 4; ++j) gld16(bgp[j], &Bs[0][wid * 32 + j * 8][0]);
#pragma unroll
  for (int j = 0; j < 2; ++j) gld16(agp[j] + BK, &As[1][wid * 16 + j * 8][0]);
#pragma unroll
  for (int j = 0; j < 4; ++j) gld16(bgp[j] + BK, &Bs[1][wid * 32 + j * 8][0]);

  for (int t = 0; t < NKT_GU; ++t) {
    int cb = t % 3;
    int sb = cb + 2; if (sb >= 3) sb -= 3;   // stage target = (t+2)%3
    int kn = (t + 2) * BK;
    bool dost = (t + 2 < NKT_GU);
    // gate: own stage(t) loads landed (newest 6 = stage(t+1) may fly)
    if (t == NKT_GU - 1) asm volatile("s_waitcnt vmcnt(0)" ::: "memory");
    else                 asm volatile("s_waitcnt vmcnt(6)" ::: "memory");
    barrier_raw();   // => ALL waves' stage(t) landed

    bhalf8 af[4], bf[4];
    // ---- phase 0: ks0, nf 0..1 ----
#pragma unroll
    for (int mf = 0; mf < 4; ++mf)
      af[mf] = *(const bhalf8*)&As[cb][wm * 64 + mf * 16 + l15][cswz * 8];
    bf[0] = *(const bhalf8*)&Bs[cb][wn * 64 + 0 + l15][cswz * 8];
    bf[1] = *(const bhalf8*)&Bs[cb][wn * 64 + 16 + l15][cswz * 8];
    if (dost) { gld16(agp[0] + kn, &As[sb][wid * 16 + 0][0]);
                gld16(bgp[0] + kn, &Bs[sb][wid * 32 + 0][0]); }
    barrier_raw();
    __builtin_amdgcn_s_setprio(1);
#pragma unroll
    for (int mf = 0; mf < 4; ++mf) {
      acc[mf][0] = __builtin_amdgcn_mfma_f32_16x16x32_bf16(af[mf], bf[0], acc[mf][0], 0, 0, 0);
      acc[mf][1] = __builtin_amdgcn_mfma_f32_16x16x32_bf16(af[mf], bf[1], acc[mf][1], 0, 0, 0);
    }
    __builtin_amdgcn_s_setprio(0);
    barrier_raw();
    // ---- phase 1: ks0, nf 2..3 ----
    bf[2] = *(const bhalf8*)&Bs[cb][wn * 64 + 32 + l15][cswz * 8];
    bf[3] = *(const bhalf8*)&Bs[cb][wn * 64 + 48 + l15][cswz * 8];
    if (dost) { gld16(agp[1] + kn, &As[sb][wid * 16 + 8][0]);
                gld16(bgp[1] + kn, &Bs[sb][wid * 32 + 8][0]); }
    barrier_raw();
    __builtin_amdgcn_s_setprio(1);
#pragma unroll
    for (int mf = 0; mf < 4; ++mf) {
      acc[mf][2] = __builtin_amdgcn_mfma_f32_16x16x32_bf16(af[mf], bf[2], acc[mf][2], 0, 0, 0);
      acc[mf][3] = __builtin_amdgcn_mfma_f32_16x16x32_bf16(af[mf], bf[3], acc[mf][3], 0, 0, 0);
    }
    __builtin_amdgcn_s_setprio(0);
    barrier_raw();
    // ---- phase 2: ks1, nf 0..1 ----
    int cz1 = cswz ^ 4;
#pragma unroll
    for (int mf = 0; mf < 4; ++mf)
      af[mf] = *(const bhalf8*)&As[cb][wm * 64 + mf * 16 + l15][cz1 * 8];
    bf[0] = *(const bhalf8*)&Bs[cb][wn * 64 + 0 + l15][cz1 * 8];
    bf[1] = *(const bhalf8*)&Bs[cb][wn * 64 + 16 + l15][cz1 * 8];
    if (dost) gld16(bgp[2] + kn, &Bs[sb][wid * 32 + 16][0]);
    barrier_raw();
    __builtin_amdgcn_s_setprio(1);
#pragma unroll
    for (int mf = 0; mf < 4; ++mf) {
      acc[mf][0] = __builtin_amdgcn_mfma_f32_16x16x32_bf16(af[mf], bf[0], acc[mf][0], 0, 0, 0);
      acc[mf][1] = __builtin_amdgcn_mfma_f32_16x16x32_bf16(af[mf], bf[1], acc[mf][1], 0, 0, 0);
    }
    __builtin_amdgcn_s_setprio(0);
    barrier_raw();
    // ---- phase 3: ks1, nf 2..3 ----
    bf[2] = *(const bhalf8*)&Bs[cb][wn * 64 + 32 + l15][cz1 * 8];
    bf[3] = *(const bhalf8*)&Bs[cb][wn * 64 + 48 + l15][cz1 * 8];
    if (dost) gld16(bgp[3] + kn, &Bs[sb][wid * 32 + 24][0]);
    barrier_raw();
    __builtin_amdgcn_s_setprio(1);
#pragma unroll
    for (int mf = 0; mf < 4; ++mf) {
      acc[mf][2] = __builtin_amdgcn_mfma_f32_16x16x32_bf16(af[mf], bf[2], acc[mf][2], 0, 0, 0);
      acc[mf][3] = __builtin_amdgcn_mfma_f32_16x16x32_bf16(af[mf], bf[3], acc[mf][3], 0, 0, 0);
    }
    __builtin_amdgcn_s_setprio(0);
    barrier_raw();
  }

  // epilogue: act = w * silu(g) * u   (nf even = gate, nf odd = up, same real cols)
#pragma unroll
  for (int mf = 0; mf < 4; ++mf) {
#pragma unroll
    for (int j = 0; j < 4; ++j) {
      int lm = wm * 64 + mf * 16 + l16 * 4 + j;
      if (lm < nrows) {
        int gr = row0 + lm;
        float w = wrow[gr];
        size_t base = (size_t)gr * II + i0r + wn * 32 + l15;
#pragma unroll
        for (int t2 = 0; t2 < 2; ++t2) {
          float g = acc[mf][2 * t2][j];
          float u = acc[mf][2 * t2 + 1][j];
          float s = g / (1.0f + __expf(-g));
          act[base + t2 * 16] = f2bf(s * u * w);
        }
      }
    }
  }
}

// ---------------- down GEMM (same 8-phase template) + scatter-add ----------------
__global__ __launch_bounds__(512) void k_down(const u16* __restrict__ act,
                                              const u16* __restrict__ dwt,
                                              const int* __restrict__ token_idx,
                                              const int* __restrict__ s_e,
                                              const int* __restrict__ s_rs,
                                              const int* __restrict__ s_rows,
                                              float* __restrict__ out) {
  int f = blockIdx.x;
  int xcd = f & 7, pos = f >> 3;           // 1152 = 8*144
  int slot = xcd * SPX + pos / NYT_DN;
  int ytile = pos % NYT_DN;
  int nrows = s_rows[slot];
  if (nrows == 0) return;
  int e = s_e[slot], row0 = s_rs[slot];
  int h0 = ytile * BNC;

  __shared__ alignas(16) u16 As[3][BM][BK];    // 48 KB
  __shared__ alignas(16) u16 Bs[3][BNC][BK];   // 96 KB

  int tid = threadIdx.x, lane = tid & 63, wid = tid >> 6;
  int l8 = lane >> 3, c8 = lane & 7, cs = c8 ^ l8;
  int wm = wid >> 2, wn = wid & 3;
  int l15 = lane & 15, l16 = lane >> 4;
  int cswz = l16 ^ (l15 & 7);

  const u16* agp[2];
#pragma unroll
  for (int j = 0; j < 2; ++j) {
    int gr = row0 + wid * 16 + j * 8 + l8;
    if (gr > NROWS - 1) gr = NROWS - 1;
    agp[j] = act + (size_t)gr * II + cs * 8;
  }
  const u16* bgp[4];
#pragma unroll
  for (int j = 0; j < 4; ++j) {
    int brow = h0 + wid * 32 + j * 8 + l8;
    bgp[j] = dwt + ((size_t)e * HH + brow) * II + cs * 8;
  }

  f32x4 acc[4][4];
#pragma unroll
  for (int a = 0; a < 4; ++a)
#pragma unroll
    for (int b = 0; b < 4; ++b) acc[a][b] = (f32x4)0.0f;

#pragma unroll
  for (int j = 0; j < 2; ++j) gld16(agp[j], &As[0][wid * 16 + j * 8][0]);
#pragma unroll
  for (int j = 0; j < 4; ++j) gld16(bgp[j], &Bs[0][wid * 32 + j * 8][0]);
#pragma unroll
  for (int j = 0; j < 2; ++j) gld16(agp[j] + BK, &As[1][wid * 16 + j * 8][0]);
#pragma unroll
  for (int j = 0; j < 4; ++j) gld16(bgp[j] + BK, &Bs[1][wid * 32 + j * 8][0]);

  for (int t = 0; t < NKT_DN; ++t) {
    int cb = t % 3;
    int sb = cb + 2; if (sb >= 3) sb -= 3;
    int kn = (t + 2) * BK;
    bool dost = (t + 2 < NKT_DN);
    if (t == NKT_DN - 1) asm volatile("s_waitcnt vmcnt(0)" ::: "memory");
    else                 asm volatile("s_waitcnt vmcnt(6)" ::: "memory");
    barrier_raw();

    bhalf8 af[4], bf[4];
    // ---- phase 0 ----
#pragma unroll
    for (int mf = 0; mf < 4; ++mf)
      af[mf] = *(const bhalf8*)&As[cb][wm * 64 + mf * 16 + l15][cswz * 8];
    bf[0] = *(const bhalf8*)&Bs[cb][wn * 64 + 0 + l15][cswz * 8];
    bf[1] = *(const bhalf8*)&Bs[cb][wn * 64 + 16 + l15][cswz * 8];
    if (dost) { gld16(agp[0] + kn, &As[sb][wid * 16 + 0][0]);
                gld16(bgp[0] + kn, &Bs[sb][wid * 32 + 0][0]); }
    barrier_raw();
    __builtin_amdgcn_s_setprio(1);
#pragma unroll
    for (int mf = 0; mf < 4; ++mf) {
      acc[mf][0] = __builtin_amdgcn_mfma_f32_16x16x32_bf16(af[mf], bf[0], acc[mf][0], 0, 0, 0);
      acc[mf][1] = __builtin_amdgcn_mfma_f32_16x16x32_bf16(af[mf], bf[1], acc[mf][1], 0, 0, 0);
    }
    __builtin_amdgcn_s_setprio(0);
    barrier_raw();
    // ---- phase 1 ----
    bf[2] = *(const bhalf8*)&Bs[cb][wn * 64 + 32 + l15][cswz * 8];
    bf[3] = *(const bhalf8*)&Bs[cb][wn * 64 + 48 + l15][cswz * 8];
    if (dost) { gld16(agp[1] + kn, &As[sb][wid * 16 + 8][0]);
                gld16(bgp[1] + kn, &Bs[sb][wid * 32 + 8][0]); }
    barrier_raw();
    __builtin_amdgcn_s_setprio(1);
#pragma unroll
    for (int mf = 0; mf < 4; ++mf) {
      acc[mf][2] = __builtin_amdgcn_mfma_f32_16x16x32_bf16(af[mf], bf[2], acc[mf][2], 0, 0, 0);
      acc[mf][3] = __builtin_amdgcn_mfma_f32_16x16x32_bf16(af[mf], bf[3], acc[mf][3], 0, 0, 0);
    }
    __builtin_amdgcn_s_setprio(0);
    barrier_raw();
    // ---- phase 2 ----
    int cz1 = cswz ^ 4;
#pragma unroll
    for (int mf = 0; mf < 4; ++mf)
      af[mf] = *(const bhalf8*)&As[cb][wm * 64 + mf * 16 + l15][cz1 * 8];
    bf[0] = *(const bhalf8*)&Bs[cb][wn * 64 + 0 + l15][cz1 * 8];
    bf[1] = *(const bhalf8*)&Bs[cb][wn * 64 + 16 + l15][cz1 * 8];
    if (dost) gld16(bgp[2] + kn, &Bs[sb][wid * 32 + 16][0]);
    barrier_raw();
    __builtin_amdgcn_s_setprio(1);
#pragma unroll
    for (int mf = 0; mf < 4; ++mf) {
      acc[mf][0] = __builtin_amdgcn_mfma_f32_16x16x32_bf16(af[mf], bf[0], acc[mf][0], 0, 0, 0);
      acc[mf][1] = __builtin_amdgcn_mfma_f32_16x16x32_bf16(af[mf], bf[1], acc[mf][1], 0, 0, 0);
    }
    __builtin_amdgcn_s_setprio(0);
    barrier_raw();
    // ---- phase 3 ----
    bf[2] = *(const bhalf8*)&Bs[cb][wn * 64 + 32 + l15][cz1 * 8];
    bf[3] = *(const bhalf8*)&Bs[cb][wn * 64 + 48 + l15][cz1 * 8];
    if (dost) gld16(bgp[3] + kn, &Bs[sb][wid * 32 + 24][0]);
    barrier_raw();
    __builtin_amdgcn_s_setprio(1);
#pragma unroll
    for (int mf = 0; mf < 4; ++mf) {
      acc[mf][2] = __builtin_amdgcn_mfma_f32_16x16x32_bf16(af[mf], bf[2], acc[mf][2], 0, 0, 0);
      acc[mf][3] = __builtin_amdgcn_mfma_f32_16x16x32_bf16(af[mf], bf[3], acc[mf][3], 0, 0, 0);
    }
    __builtin_amdgcn_s_setprio(0);
    barrier_raw();
  }

#pragma unroll
  for (int mf = 0; mf < 4; ++mf) {
#pragma unroll
    for (int j = 0; j < 4; ++j) {
      int lm = wm * 64 + mf * 16 + l16 * 4 + j;
      if (lm < nrows) {
        int tok = token_idx[row0 + lm];
        size_t base = (size_t)tok * HH + h0 + wn * 64 + l15;
#pragma unroll
        for (int nf = 0; nf < 4; ++nf)
          atomicAdd(&out[base + nf * 16], acc[mf][nf][j]);
      }
    }
  }
}

extern "C" void kernel_launch(void* const* d_in, const int* in_sizes, int n_in,
                              void* d_out, int out_size, void* d_ws, size_t ws_size,
                              hipStream_t stream) {
  const int* sel = (const int*)d_in[0];
  const float* hs = (const float*)d_in[1];
  const float* rw = (const float*)d_in[2];
  const float* gw = (const float*)d_in[3];
  const float* uw = (const float*)d_in[4];
  const float* dw = (const float*)d_in[5];
  float* out = (float*)d_out;

  char* ws = (char*)d_ws;
  size_t o = 0;
  u16* hsb = (u16*)(ws + o); o += (size_t)TT * HH * 2;            // 32 MB
  u16* guw = (u16*)(ws + o); o += (size_t)NE * IIC * HH * 2;      // 88 MB
  u16* dwt = (u16*)(ws + o); o += (size_t)NE * HH * II * 2;       // 44 MB
  u16* act = (u16*)(ws + o); o += (size_t)NROWS * II * 2;         // 44 MB
  int* token_idx = (int*)(ws + o); o += (size_t)NROWS * 4;
  float* wrow = (float*)(ws + o); o += (size_t)NROWS * 4;
  int* s_e = (int*)(ws + o); o += MAX_SLOTS * 4;
  int* s_rs = (int*)(ws + o); o += MAX_SLOTS * 4;
  int* s_rows = (int*)(ws + o); o += MAX_SLOTS * 4;
  (void)ws_size; (void)in_sizes; (void)n_in; (void)out_size;

  // fp32 -> bf16 conversions (+ layout transforms)
  k_cvt_hs<<<(TT * HH) / 2048, 256, 0, stream>>>(hs, hsb);
  dim3 g1(II / 64, HH / 64, NE);
  k_tconv_gu<<<g1, 256, 0, stream>>>(gw, guw, 0);
  k_tconv_gu<<<g1, 256, 0, stream>>>(uw, guw, 1);
  dim3 g2(HH / 64, II / 64, NE);
  k_tconv<<<g2, 256, 0, stream>>>(dw, dwt, II, HH);

  // routing + zero output
  k_route<<<1, 256, 0, stream>>>(sel, rw, token_idx, wrow, s_e, s_rs, s_rows);
  hipMemsetAsync(d_out, 0, (size_t)TT * HH * 4, stream);

  // gate/up GEMM + SwiGLU  (512 threads, 8-phase, XCD swizzle)
  k_gu<<<MAX_SLOTS * NYT_GU, 512, 0, stream>>>(hsb, guw, token_idx, wrow,
                                               s_e, s_rs, s_rows, act);

  // down GEMM + scatter-add
  k_down<<<MAX_SLOTS * NYT_DN, 512, 0, stream>>>(act, dwt, token_idx,
                                                 s_e, s_rs, s_rows, out);
}

// Round 10
// 566.922 us; speedup vs baseline: 1.4221x; 1.4221x over previous
//
#include <hip/hip_runtime.h>
#include <stdint.h>

// Problem constants (fixed shapes)
#define TT 8192      // tokens = B*S
#define HH 2048      // hidden dim
#define II 1408      // intermediate dim
#define NE 8         // experts
#define NROWS (TT*2) // (token, slot) rows = 16384
#define BM 128       // row tile
#define BK 64        // k tile
#define BND 128      // k_down N tile
#define MAX_SLOTS 144
#define NKT_GU (HH/BK)   // 32
#define NKT_DN (II/BK)   // 22
#define NYT_GU (II/64)   // 22  N-tiles in k_gu (N=64 per B-matrix, gate+up)
#define NYT_DN (HH/BND)  // 16  N-tiles in k_down
#define SPX (MAX_SLOTS/8)  // 18 slots per XCD

typedef unsigned short u16;
typedef __attribute__((ext_vector_type(8))) __bf16 bhalf8;
typedef __attribute__((ext_vector_type(4))) float f32x4;
typedef __attribute__((ext_vector_type(4))) float float4v;
typedef __attribute__((ext_vector_type(4))) int int4v;

__device__ __forceinline__ u16 f2bf(float f) {
  union { float f; unsigned u; } v; v.f = f;
  return (u16)((v.u + 0x7FFFu + ((v.u >> 16) & 1u)) >> 16);  // RNE
}

__device__ __forceinline__ void gld16(const void* g, void* l) {
  __builtin_amdgcn_global_load_lds(
      (const __attribute__((address_space(1))) unsigned int*)g,
      (__attribute__((address_space(3))) unsigned int*)l, 16, 0, 0);
}

// ---------------- hidden_states fp32 -> bf16 ----------------
__global__ __launch_bounds__(256) void k_cvt_hs(const float* __restrict__ in,
                                                u16* __restrict__ out) {
  size_t i = ((size_t)blockIdx.x * 256 + threadIdx.x) * 8;
  float4v a = *(const float4v*)(in + i);
  float4v b = *(const float4v*)(in + i + 4);
  u16 o[8];
  o[0] = f2bf(a.x); o[1] = f2bf(a.y); o[2] = f2bf(a.z); o[3] = f2bf(a.w);
  o[4] = f2bf(b.x); o[5] = f2bf(b.y); o[6] = f2bf(b.z); o[7] = f2bf(b.w);
  *(int4v*)(out + i) = *(const int4v*)o;
}

// ------- down weight fp32 [E][R][C] -> bf16 transposed [E][C][R] -------
__global__ __launch_bounds__(256) void k_tconv(const float* __restrict__ in,
                                               u16* __restrict__ out,
                                               int R, int C) {
  __shared__ float t[64][65];
  int e = blockIdx.z;
  int r0 = blockIdx.y * 64, c0 = blockIdx.x * 64;
  const float* ip = in + (size_t)e * R * C;
  u16* op = out + (size_t)e * R * C;
  int tid = threadIdx.x;
  int rr = tid >> 4, c4 = (tid & 15) * 4;
#pragma unroll
  for (int j = 0; j < 4; ++j) {
    float4v v = *(const float4v*)&ip[(size_t)(r0 + rr + 16 * j) * C + c0 + c4];
    t[rr + 16 * j][c4 + 0] = v.x;
    t[rr + 16 * j][c4 + 1] = v.y;
    t[rr + 16 * j][c4 + 2] = v.z;
    t[rr + 16 * j][c4 + 3] = v.w;
  }
  __syncthreads();
  int cc = tid >> 2, rb = (tid & 3) * 16;
  u16 buf[16];
#pragma unroll
  for (int i = 0; i < 16; ++i) buf[i] = f2bf(t[rb + i][cc]);
  u16* p = op + (size_t)(c0 + cc) * R + r0 + rb;
  *(int4v*)p = *(const int4v*)&buf[0];
  *(int4v*)(p + 8) = *(const int4v*)&buf[8];
}

// ------- gate+up fp32 [E][H][I] -> bf16 [E][I][H], one fused launch -------
// blockIdx.z in [0,16): z&7 = expert, z>>3 = {0:gate, 1:up}
__global__ __launch_bounds__(256) void k_tconv2(const float* __restrict__ gw,
                                                const float* __restrict__ uw,
                                                u16* __restrict__ gwt,
                                                u16* __restrict__ uwt) {
  __shared__ float t[64][65];
  const int R = HH, C = II;
  int z = blockIdx.z;
  int e = z & 7;
  const float* in = (z < 8) ? gw : uw;
  u16* out = (z < 8) ? gwt : uwt;
  int r0 = blockIdx.y * 64, c0 = blockIdx.x * 64;
  const float* ip = in + (size_t)e * R * C;
  u16* op = out + (size_t)e * R * C;
  int tid = threadIdx.x;
  int rr = tid >> 4, c4 = (tid & 15) * 4;
#pragma unroll
  for (int j = 0; j < 4; ++j) {
    float4v v = *(const float4v*)&ip[(size_t)(r0 + rr + 16 * j) * C + c0 + c4];
    t[rr + 16 * j][c4 + 0] = v.x;
    t[rr + 16 * j][c4 + 1] = v.y;
    t[rr + 16 * j][c4 + 2] = v.z;
    t[rr + 16 * j][c4 + 3] = v.w;
  }
  __syncthreads();
  int cc = tid >> 2, rb = (tid & 3) * 16;
  u16 buf[16];
#pragma unroll
  for (int i = 0; i < 16; ++i) buf[i] = f2bf(t[rb + i][cc]);
  u16* p = op + (size_t)(c0 + cc) * R + r0 + rb;
  *(int4v*)p = *(const int4v*)&buf[0];
  *(int4v*)(p + 8) = *(const int4v*)&buf[8];
}

// ---------------- routing: gather rows by expert ----------------
__global__ __launch_bounds__(256) void k_route(const int* __restrict__ sel,
                                               const float* __restrict__ rw,
                                               int* __restrict__ token_idx,
                                               float* __restrict__ wrow,
                                               int* __restrict__ s_e,
                                               int* __restrict__ s_rs,
                                               int* __restrict__ s_rows) {
  __shared__ int cnt[NE], offs[NE + 1], cursor[NE];
  int tid = threadIdx.x;
  if (tid < NE) cnt[tid] = 0;
  __syncthreads();
  for (int i = tid; i < NROWS; i += 256) atomicAdd(&cnt[sel[i]], 1);
  __syncthreads();
  if (tid == 0) {
    int o = 0;
    for (int e = 0; e < NE; ++e) { offs[e] = o; o += cnt[e]; }
    offs[NE] = o;
    int ns = 0;
    for (int e = 0; e < NE; ++e) {
      for (int t = 0; t < cnt[e]; t += BM) {
        s_e[ns] = e;
        s_rs[ns] = offs[e] + t;
        s_rows[ns] = (cnt[e] - t < BM) ? (cnt[e] - t) : BM;
        ns++;
      }
    }
    for (; ns < MAX_SLOTS; ++ns) s_rows[ns] = 0;
  }
  __syncthreads();
  if (tid < NE) cursor[tid] = offs[tid];
  __syncthreads();
  for (int i = tid; i < NROWS; i += 256) {
    int e = sel[i];
    int r = atomicAdd(&cursor[e], 1);
    token_idx[r] = i >> 1;   // token id
    wrow[r] = rw[i];         // routing weight for this slot
  }
}

// ---------------- gate/up GEMM + SwiGLU epilogue (R6 verbatim) ----------------
// m97 structure: single-buffered LDS, stage -> barrier -> MFMA -> barrier.
// 1D grid, XCD-aware swizzle: xcd = f&7 owns 18 contiguous slots.
__global__ __launch_bounds__(256, 4) void k_gu(const u16* __restrict__ hsb,
                                               const u16* __restrict__ gwt,
                                               const u16* __restrict__ uwt,
                                               const int* __restrict__ token_idx,
                                               const float* __restrict__ wrow,
                                               const int* __restrict__ s_e,
                                               const int* __restrict__ s_rs,
                                               const int* __restrict__ s_rows,
                                               u16* __restrict__ act) {
  int f = blockIdx.x;
  int xcd = f & 7;
  int pos = f >> 3;                 // 0..395
  int slot = xcd * SPX + pos / NYT_GU;
  int ytile = pos % NYT_GU;
  int nrows = s_rows[slot];
  if (nrows == 0) return;
  int e = s_e[slot];
  int row0 = s_rs[slot];
  int i0 = ytile * 64;

  __shared__ alignas(16) u16 As[BM][BK];   // 16 KB
  __shared__ alignas(16) u16 Bg[64][BK];   // 8 KB
  __shared__ alignas(16) u16 Bu[64][BK];   // 8 KB  -> 32 KB total

  int tid = threadIdx.x;
  int lane = tid & 63;
  int wid = tid >> 6;
  int l8 = lane >> 3;
  int c8 = lane & 7;
  int cs = c8 ^ l8;            // swizzled source chunk (dest LDS linear, rule #21)

  const u16* agp[4];
#pragma unroll
  for (int j = 0; j < 4; ++j) {
    int gr = row0 + wid * 32 + j * 8 + l8;
    if (gr > NROWS - 1) gr = NROWS - 1;
    int tok = token_idx[gr];
    agp[j] = hsb + (size_t)tok * HH + cs * 8;
  }
  const u16* ggp[2]; const u16* ugp[2];
#pragma unroll
  for (int j = 0; j < 2; ++j) {
    size_t off = ((size_t)e * II + i0 + wid * 16 + j * 8 + l8) * HH + cs * 8;
    ggp[j] = gwt + off;
    ugp[j] = uwt + off;
  }

  int wm = wid >> 1, wn = wid & 1;
  int l15 = lane & 15, l16 = lane >> 4;

  f32x4 accg[4][2], accu[4][2];
#pragma unroll
  for (int a = 0; a < 4; ++a)
#pragma unroll
    for (int b = 0; b < 2; ++b) { accg[a][b] = (f32x4)0.0f; accu[a][b] = (f32x4)0.0f; }

  for (int kt = 0; kt < NKT_GU; ++kt) {
    int k0 = kt * BK;
#pragma unroll
    for (int j = 0; j < 4; ++j) gld16(agp[j] + k0, &As[wid * 32 + j * 8][0]);
#pragma unroll
    for (int j = 0; j < 2; ++j) {
      gld16(ggp[j] + k0, &Bg[wid * 16 + j * 8][0]);
      gld16(ugp[j] + k0, &Bu[wid * 16 + j * 8][0]);
    }
    __syncthreads();
#pragma unroll
    for (int ks = 0; ks < 2; ++ks) {
      bhalf8 af[4], bgf[2], buf_[2];
#pragma unroll
      for (int mf = 0; mf < 4; ++mf) {
        int row = wm * 64 + mf * 16 + l15;
        int c = (ks * 4 + l16) ^ (row & 7);
        af[mf] = *(const bhalf8*)&As[row][c * 8];
      }
#pragma unroll
      for (int nf = 0; nf < 2; ++nf) {
        int row = wn * 32 + nf * 16 + l15;
        int c = (ks * 4 + l16) ^ (row & 7);
        bgf[nf] = *(const bhalf8*)&Bg[row][c * 8];
        buf_[nf] = *(const bhalf8*)&Bu[row][c * 8];
      }
#pragma unroll
      for (int mf = 0; mf < 4; ++mf)
#pragma unroll
        for (int nf = 0; nf < 2; ++nf) {
          accg[mf][nf] = __builtin_amdgcn_mfma_f32_16x16x32_bf16(af[mf], bgf[nf], accg[mf][nf], 0, 0, 0);
          accu[mf][nf] = __builtin_amdgcn_mfma_f32_16x16x32_bf16(af[mf], buf_[nf], accu[mf][nf], 0, 0, 0);
        }
    }
    __syncthreads();
  }

  // epilogue: act = w * silu(g) * u
#pragma unroll
  for (int mf = 0; mf < 4; ++mf) {
#pragma unroll
    for (int j = 0; j < 4; ++j) {
      int lm = wm * 64 + mf * 16 + l16 * 4 + j;
      if (lm < nrows) {
        int gr = row0 + lm;
        float w = wrow[gr];
        size_t base = (size_t)gr * II + i0 + wn * 32 + l15;
#pragma unroll
        for (int nf = 0; nf < 2; ++nf) {
          float g = accg[mf][nf][j];
          float u = accu[mf][nf][j];
          float s = g / (1.0f + __expf(-g));
          act[base + nf * 16] = f2bf(s * u * w);
        }
      }
    }
  }
}

// ---------------- down GEMM (R7's BN=128 variant) + scatter-add ----------------
// 32 MFMA : 8 gld16 per K-tile per wave (m97-optimal intensity).
__global__ __launch_bounds__(256, 3) void k_down(const u16* __restrict__ act,
                                                 const u16* __restrict__ dwt,
                                                 const int* __restrict__ token_idx,
                                                 const int* __restrict__ s_e,
                                                 const int* __restrict__ s_rs,
                                                 const int* __restrict__ s_rows,
                                                 float* __restrict__ out) {
  int f = blockIdx.x;
  int xcd = f & 7;
  int pos = f >> 3;                 // 0..287
  int slot = xcd * SPX + pos / NYT_DN;
  int ytile = pos % NYT_DN;
  int nrows = s_rows[slot];
  if (nrows == 0) return;
  int e = s_e[slot];
  int row0 = s_rs[slot];
  int h0 = ytile * BND;

  __shared__ alignas(16) u16 As[BM][BK];    // 16 KB
  __shared__ alignas(16) u16 Bs[BND][BK];   // 16 KB -> 32 KB total

  int tid = threadIdx.x;
  int lane = tid & 63;
  int wid = tid >> 6;
  int l8 = lane >> 3;
  int c8 = lane & 7;
  int cs = c8 ^ l8;

  const u16* agp[4];
#pragma unroll
  for (int j = 0; j < 4; ++j) {
    int gr = row0 + wid * 32 + j * 8 + l8;
    if (gr > NROWS - 1) gr = NROWS - 1;
    agp[j] = act + (size_t)gr * II + cs * 8;
  }
  const u16* bgp[4];
#pragma unroll
  for (int j = 0; j < 4; ++j)
    bgp[j] = dwt + ((size_t)e * HH + h0 + wid * 32 + j * 8 + l8) * II + cs * 8;

  int wm = wid >> 1, wn = wid & 1;
  int l15 = lane & 15, l16 = lane >> 4;

  f32x4 acc[4][4];
#pragma unroll
  for (int a = 0; a < 4; ++a)
#pragma unroll
    for (int b = 0; b < 4; ++b) acc[a][b] = (f32x4)0.0f;

  for (int kt = 0; kt < NKT_DN; ++kt) {
    int k0 = kt * BK;
#pragma unroll
    for (int j = 0; j < 4; ++j) {
      gld16(agp[j] + k0, &As[wid * 32 + j * 8][0]);
      gld16(bgp[j] + k0, &Bs[wid * 32 + j * 8][0]);
    }
    __syncthreads();
#pragma unroll
    for (int ks = 0; ks < 2; ++ks) {
      bhalf8 af[4], bf[4];
#pragma unroll
      for (int mf = 0; mf < 4; ++mf) {
        int row = wm * 64 + mf * 16 + l15;
        int c = (ks * 4 + l16) ^ (row & 7);
        af[mf] = *(const bhalf8*)&As[row][c * 8];
      }
#pragma unroll
      for (int nf = 0; nf < 4; ++nf) {
        int row = wn * 64 + nf * 16 + l15;
        int c = (ks * 4 + l16) ^ (row & 7);
        bf[nf] = *(const bhalf8*)&Bs[row][c * 8];
      }
#pragma unroll
      for (int mf = 0; mf < 4; ++mf)
#pragma unroll
        for (int nf = 0; nf < 4; ++nf)
          acc[mf][nf] = __builtin_amdgcn_mfma_f32_16x16x32_bf16(af[mf], bf[nf], acc[mf][nf], 0, 0, 0);
    }
    __syncthreads();
  }

#pragma unroll
  for (int mf = 0; mf < 4; ++mf) {
#pragma unroll
    for (int j = 0; j < 4; ++j) {
      int lm = wm * 64 + mf * 16 + l16 * 4 + j;
      if (lm < nrows) {
        int tok = token_idx[row0 + lm];
        size_t base = (size_t)tok * HH + h0 + wn * 64 + l15;
#pragma unroll
        for (int nf = 0; nf < 4; ++nf)
          atomicAdd(&out[base + nf * 16], acc[mf][nf][j]);
      }
    }
  }
}

extern "C" void kernel_launch(void* const* d_in, const int* in_sizes, int n_in,
                              void* d_out, int out_size, void* d_ws, size_t ws_size,
                              hipStream_t stream) {
  const int* sel = (const int*)d_in[0];
  const float* hs = (const float*)d_in[1];
  const float* rw = (const float*)d_in[2];
  const float* gw = (const float*)d_in[3];
  const float* uw = (const float*)d_in[4];
  const float* dw = (const float*)d_in[5];
  float* out = (float*)d_out;

  char* ws = (char*)d_ws;
  size_t o = 0;
  u16* hsb = (u16*)(ws + o); o += (size_t)TT * HH * 2;           // 32 MB
  u16* gwt = (u16*)(ws + o); o += (size_t)NE * HH * II * 2;      // 44 MB
  u16* uwt = (u16*)(ws + o); o += (size_t)NE * HH * II * 2;      // 44 MB
  u16* dwt = (u16*)(ws + o); o += (size_t)NE * HH * II * 2;      // 44 MB
  u16* act = (u16*)(ws + o); o += (size_t)NROWS * II * 2;        // 44 MB
  int* token_idx = (int*)(ws + o); o += (size_t)NROWS * 4;
  float* wrow = (float*)(ws + o); o += (size_t)NROWS * 4;
  int* s_e = (int*)(ws + o); o += MAX_SLOTS * 4;
  int* s_rs = (int*)(ws + o); o += MAX_SLOTS * 4;
  int* s_rows = (int*)(ws + o); o += MAX_SLOTS * 4;
  (void)ws_size; (void)in_sizes; (void)n_in; (void)out_size;

  // fp32 -> bf16 conversions (+ weight transpose to [N][K])
  k_cvt_hs<<<(TT * HH) / 2048, 256, 0, stream>>>(hs, hsb);
  dim3 g1(II / 64, HH / 64, 2 * NE);
  k_tconv2<<<g1, 256, 0, stream>>>(gw, uw, gwt, uwt);
  dim3 g2(HH / 64, II / 64, NE);
  k_tconv<<<g2, 256, 0, stream>>>(dw, dwt, II, HH);

  // routing + zero output
  k_route<<<1, 256, 0, stream>>>(sel, rw, token_idx, wrow, s_e, s_rs, s_rows);
  hipMemsetAsync(d_out, 0, (size_t)TT * HH * 4, stream);

  // gate/up GEMM + SwiGLU  (1D grid, XCD swizzle)
  k_gu<<<MAX_SLOTS * NYT_GU, 256, 0, stream>>>(hsb, gwt, uwt, token_idx, wrow,
                                               s_e, s_rs, s_rows, act);

  // down GEMM with scatter-add  (1D grid, XCD swizzle)
  k_down<<<MAX_SLOTS * NYT_DN, 256, 0, stream>>>(act, dwt, token_idx,
                                                 s_e, s_rs, s_rows, out);
}